// Round 7
// baseline (229.743 us; speedup 1.0000x reference)
//
#include <hip/hip_runtime.h>

#define N 4096
#define CORE_W 116        // core columns per strip
#define NSTRIP 36         // 36*116 = 4176 >= 4096
#define ROWS 18           // output rows per wave (28 ingest steps)
#define NCHUNK 228        // 228*18 = 4104 >= 4096
#define ITERS 5
#define NSLOT 32          // atomic spreading slots
#define WPB 4             // waves per 256-thread block (independent waves;
                          // beats the ~16 single-wave-workgroup/CU slot cap)

// One wave (64 lanes) owns a 128-wide column strip (2 cols/lane, global
// cols [x0, x0+128), x0 = strip*116 - 6, core cols [x0+6, x0+122)). It
// marches down rows keeping the 5-stage recurrence in rolling REGISTERS:
// at ingest row t it computes iter1 row t-1 ... iter5 row t-5. Horizontal
// stencil via __shfl lane+-1 (1 col/stage edge contamination; core margin 6).
// Vertical: rolling buffers with compile-time mod indices (6x unroll).
// Warm-up: correctness cascade gives correct_j(r) for r >= t0+j, so t0 =
// R0-5 makes iter5 exact from row R0; zero-init state is finite garbage
// that only reaches iter5 rows < R0 (discarded by row guards). gt prologue
// rows provably uninfluential -> zeros. No LDS, no barriers; the 4 waves
// of a block are fully independent.

typedef float2 f2;
__device__ __forceinline__ f2 mkf2(float a, float b){ f2 r; r.x=a; r.y=b; return r; }

__device__ __forceinline__ f2 hsum(f2 v) {
    float m = v.x + v.y;
    float L = __shfl_up(v.y, 1);     // lane l-1's right col
    float R = __shfl_down(v.x, 1);   // lane l+1's left col
    return mkf2(L + m, m + R);
}

__device__ __forceinline__ f2 stepf(f2 p, f2 d, f2 g, f2* fn) {
    const float C1 = 28.853900817779268f;   // 20*log2(e)
    const float C2 = 14.426950408889634f;   // 10*log2(e)
    f2 o, f;
    {
        float dd = fminf(fmaxf(d.x, 0.f), 1.f);
        float u  = __builtin_fmaf(p.x - dd, C1, C2);
        float sh = __builtin_amdgcn_rcpf(1.f + __builtin_amdgcn_exp2f(u));
        f.x = g.x * sh; o.x = p.x + f.x;
    }
    {
        float dd = fminf(fmaxf(d.y, 0.f), 1.f);
        float u  = __builtin_fmaf(p.y - dd, C1, C2);
        float sh = __builtin_amdgcn_rcpf(1.f + __builtin_amdgcn_exp2f(u));
        f.y = g.y * sh; o.y = p.y + f.y;
    }
    *fn = f;
    return o;
}

__device__ __forceinline__ f2 ldrow(const float* __restrict__ base, int row,
                                    int gc, bool edge) {
    if (row < 0 || row >= N) return mkf2(0.f, 0.f);
    if (!edge) return *(const f2*)(base + (size_t)row * N + gc);  // gc even -> aligned
    float a = 0.f, b = 0.f;
    if (gc >= 0 && gc < N)         a = base[(size_t)row * N + gc];
    if (gc + 1 >= 0 && gc + 1 < N) b = base[(size_t)row * N + gc + 1];
    return mkf2(a, b);
}

__global__ __launch_bounds__(64 * WPB) void wlc_main(
    const float* __restrict__ pred,
    const float* __restrict__ gt,
    float* __restrict__ ws)
{
    const int tid  = threadIdx.x;
    const int lane = tid & 63;
    const int wid  = blockIdx.x * WPB + (tid >> 6);   // global wave id
    const int strip = wid % NSTRIP;
    const int chunk = wid / NSTRIP;

    const int x0 = strip * CORE_W - 6;
    const int gc = x0 + 2 * lane;
    const bool edge = (strip == 0) || (strip == NSTRIP - 1);

    const int R0 = chunk * ROWS;
    const int R1 = min(R0 + ROWS, N);
    const int t0 = R0 - 5;           // 5-row warm-up (cascade-minimal)
    const int t1 = R1 + 5;           // 5-row drain (pipeline depth)

    // column accumulation masks: core cols -> lanes 3..60
    const float colm = (lane >= 3 && lane <= 60) ? 1.f : 0.f;
    const float m0 = (gc     < N) ? colm : 0.f;
    const float m1 = (gc + 1 < N) ? colm : 0.f;

    // rolling state (all registers; zero-init -> finite warm-up garbage)
    f2 pr[6], gb[6];
    f2 h0[3], h1[3], h2[3], h3[3], h4[3];
    f2 o1[2], o2[2], o3[2], o4[2];
#pragma unroll
    for (int i = 0; i < 6; ++i) { pr[i] = mkf2(0,0); gb[i] = mkf2(0,0); }
#pragma unroll
    for (int i = 0; i < 3; ++i) { h0[i]=h1[i]=h2[i]=h3[i]=h4[i]=mkf2(0,0); }
#pragma unroll
    for (int i = 0; i < 2; ++i) { o1[i]=o2[i]=o3[i]=o4[i]=mkf2(0,0); }

    // prologue: slots are relative to (t - t0): row t0 -> slot 2, t0+1 -> 3.
    // gt prologue rows (< R0-4) are provably uninfluential -> stay zero;
    // real gt rows R0-4..R1+3 arrive via the t+1 prefetch.
    pr[2] = ldrow(pred, t0,     gc, edge);
    pr[3] = ldrow(pred, t0 + 1, gc, edge);

    float s1a=0.f, s2a=0.f, s3a=0.f, s4a=0.f, s5a=0.f, gsa=0.f;

    // compile-time slot macros for row t+o (valid o >= -5)
#define S6(o) ((8 + k + (o)) % 6)
#define S3(o) ((8 + k + (o)) % 3)
#define S2(o) ((8 + k + (o)) % 2)

    for (int tb = t0; tb < t1; tb += 6) {
#pragma unroll
        for (int k = 0; k < 6; ++k) {
            const int t = tb + k;
            if (t < t1) {
                // save gt row t-5 before its slot is reloaded with row t+1
                const f2 g5 = gb[S6(-5)];
                // prefetch (2-row slack); trim useless drain loads
                if (t + 2 <= R1 + 4) pr[S6(2)] = ldrow(pred, t + 2, gc, edge);
                if (t + 1 <= R1 + 3) gb[S6(1)] = ldrow(gt,   t + 1, gc, edge);

                // h-sum of input row t
                h0[S3(0)] = hsum(pr[S6(0)]);

                f2 d, fn, o;
                // stage 1: row t-1
                d = mkf2(h0[0].x + h0[1].x + h0[2].x, h0[0].y + h0[1].y + h0[2].y);
                o = stepf(pr[S6(-1)], d, gb[S6(-1)], &fn);
                { int r = t - 1; if (r >= R0 && r < R1) s1a += fn.x*m0 + fn.y*m1; }
                h1[S3(-1)] = hsum(o);  o1[S2(-1)] = o;

                // stage 2: row t-2
                d = mkf2(h1[0].x + h1[1].x + h1[2].x, h1[0].y + h1[1].y + h1[2].y);
                o = stepf(o1[S2(-2)], d, gb[S6(-2)], &fn);
                { int r = t - 2; if (r >= R0 && r < R1) s2a += fn.x*m0 + fn.y*m1; }
                h2[S3(-2)] = hsum(o);  o2[S2(-2)] = o;

                // stage 3: row t-3
                d = mkf2(h2[0].x + h2[1].x + h2[2].x, h2[0].y + h2[1].y + h2[2].y);
                o = stepf(o2[S2(-3)], d, gb[S6(-3)], &fn);
                { int r = t - 3; if (r >= R0 && r < R1) s3a += fn.x*m0 + fn.y*m1; }
                h3[S3(-3)] = hsum(o);  o3[S2(-3)] = o;

                // stage 4: row t-4
                d = mkf2(h3[0].x + h3[1].x + h3[2].x, h3[0].y + h3[1].y + h3[2].y);
                o = stepf(o3[S2(-4)], d, gb[S6(-4)], &fn);
                { int r = t - 4; if (r >= R0 && r < R1) s4a += fn.x*m0 + fn.y*m1; }
                h4[S3(-4)] = hsum(o);  o4[S2(-4)] = o;

                // stage 5: row t-5 (output not fed forward)
                d = mkf2(h4[0].x + h4[1].x + h4[2].x, h4[0].y + h4[1].y + h4[2].y);
                o = stepf(o4[S2(-5)], d, g5, &fn);
                { int r = t - 5;
                  if (r >= R0 && r < R1) {
                      s5a += fn.x*m0 + fn.y*m1;
                      gsa += g5.x*m0 + g5.y*m1;
                  } }
            }
        }
    }
#undef S6
#undef S3
#undef S2

    // per-wave reduction -> 6 atomics, spread over NSLOT slot copies
    float vals[6] = {gsa, s1a, s2a, s3a, s4a, s5a};
    const int slot = wid & (NSLOT - 1);
#pragma unroll
    for (int kk = 0; kk < 6; ++kk) {
        float v = vals[kk];
#pragma unroll
        for (int off = 32; off > 0; off >>= 1)
            v += __shfl_down(v, off, 64);
        if (lane == 0) atomicAdd(&ws[slot * 32 + kk], v);
    }
}

__global__ void wlc_final(const float* __restrict__ ws, float* __restrict__ out)
{
    float t[6] = {0.f, 0.f, 0.f, 0.f, 0.f, 0.f};
    for (int s = 0; s < NSLOT; ++s)
#pragma unroll
        for (int kk = 0; kk < 6; ++kk)
            t[kk] += ws[s * 32 + kk];
    out[0] = (1.f * t[1] + 4.f * t[2] + 9.f * t[3] + 16.f * t[4] + 25.f * t[5]) / t[0];
}

extern "C" void kernel_launch(void* const* d_in, const int* in_sizes, int n_in,
                              void* d_out, int out_size, void* d_ws, size_t ws_size,
                              hipStream_t stream)
{
    const float* pred = (const float*)d_in[0];
    const float* gtp  = (const float*)d_in[1];
    float* ws = (float*)d_ws;

    hipMemsetAsync(d_ws, 0, NSLOT * 32 * sizeof(float), stream);

    // NSTRIP*NCHUNK = 8208 waves = 2052 blocks of 4 independent waves
    wlc_main<<<dim3((NSTRIP * NCHUNK) / WPB), 64 * WPB, 0, stream>>>(pred, gtp, ws);
    wlc_final<<<1, 1, 0, stream>>>(ws, (float*)d_out);
}